// Round 1
// baseline (667.560 us; speedup 1.0000x reference)
//
#include <hip/hip_runtime.h>
#include <math.h>

#define NB1 1024          // blocks in pass 1
#define TPB 256           // threads per block
#define HALVES_PER_BLOCK (TPB / 32)
#define NCAND (NB1 * 5)

constexpr float EPS = 1e-6f;

__device__ __forceinline__ bool better(float v, int i, float bv, int bi) {
    // strictly-greater wins; on exact tie, lower row index wins (jax top_k order)
    return (v > bv) || (v == bv && i < bi);
}

__global__ __launch_bounds__(TPB) void sim_block_topk(
    const float* __restrict__ W, const int* __restrict__ qidx,
    int V, float* __restrict__ bv, int* __restrict__ bi)
{
    const int tid  = threadIdx.x;
    const int l    = tid & 31;               // lane within 32-lane half
    const int half = tid >> 5;               // 0..7 within block
    const int halfGlobal = blockIdx.x * HALVES_PER_BLOCK + half;
    const int nHalves    = NB1 * HALVES_PER_BLOCK;

    const int q = qidx[0];
    const float4 qv = ((const float4*)(W + (size_t)q * 128))[l];

    // ||q|| via butterfly reduce within the 32-lane half (xor masks <=16 stay in-half)
    float qn2 = qv.x*qv.x + qv.y*qv.y + qv.z*qv.z + qv.w*qv.w;
    #pragma unroll
    for (int m = 16; m >= 1; m >>= 1) qn2 += __shfl_xor(qn2, m);
    const float qn = sqrtf(qn2);

    // per-leader register top-5 (constant-indexed after unroll -> stays in VGPRs)
    float tv[5]; int ti[5];
    #pragma unroll
    for (int j = 0; j < 5; j++) { tv[j] = -INFINITY; ti[j] = 0x7fffffff; }

    for (int row = halfGlobal; row < V; row += nHalves) {
        const float4 wv = ((const float4*)(W + (size_t)row * 128))[l];
        float dot = wv.x*qv.x + wv.y*qv.y + wv.z*qv.z + wv.w*qv.w;
        float nr  = wv.x*wv.x + wv.y*wv.y + wv.z*wv.z + wv.w*wv.w;
        #pragma unroll
        for (int m = 16; m >= 1; m >>= 1) {
            dot += __shfl_xor(dot, m);
            nr  += __shfl_xor(nr,  m);
        }
        if (l == 0) {
            float sim = dot / fmaxf(qn * sqrtf(nr), EPS);
            if (sim > tv[4]) {                       // common-case reject
                float nv = sim; int ni = row;
                #pragma unroll
                for (int j = 0; j < 5; j++) {        // bubble-insert, keeps sorted desc
                    bool b = better(nv, ni, tv[j], ti[j]);
                    float ov = tv[j]; int oi = ti[j];
                    if (b) { tv[j] = nv; ti[j] = ni; nv = ov; ni = oi; }
                }
            }
        }
    }

    // block combine: 8 halves x 5 -> block top-5
    __shared__ float s_v[HALVES_PER_BLOCK * 5];
    __shared__ int   s_i[HALVES_PER_BLOCK * 5];
    if (l == 0) {
        #pragma unroll
        for (int j = 0; j < 5; j++) { s_v[half*5 + j] = tv[j]; s_i[half*5 + j] = ti[j]; }
    }
    __syncthreads();
    if (tid == 0) {
        for (int k = 0; k < 5; k++) {
            float cv = -INFINITY; int ci = 0x7fffffff; int cp = 0;
            for (int e = 0; e < HALVES_PER_BLOCK * 5; e++) {
                if (better(s_v[e], s_i[e], cv, ci)) { cv = s_v[e]; ci = s_i[e]; cp = e; }
            }
            bv[blockIdx.x*5 + k] = cv;
            bi[blockIdx.x*5 + k] = ci;
            s_v[cp] = -INFINITY;
        }
    }
}

__global__ __launch_bounds__(256) void final_topk(
    const float* __restrict__ bv, const int* __restrict__ bi,
    float* __restrict__ out)
{
    __shared__ float s_v[NCAND];
    __shared__ int   s_i[NCAND];
    __shared__ float sw_v[4];
    __shared__ int   sw_i[4], sw_p[4];

    const int tid = threadIdx.x;
    for (int e = tid; e < NCAND; e += 256) { s_v[e] = bv[e]; s_i[e] = bi[e]; }
    __syncthreads();

    for (int k = 0; k < 5; k++) {
        float v = -INFINITY; int i = 0x7fffffff; int p = 0;
        for (int e = tid; e < NCAND; e += 256) {
            if (better(s_v[e], s_i[e], v, i)) { v = s_v[e]; i = s_i[e]; p = e; }
        }
        // 64-lane wave reduce of (v,i,p)
        #pragma unroll
        for (int m = 32; m >= 1; m >>= 1) {
            float ov = __shfl_xor(v, m);
            int   oi = __shfl_xor(i, m);
            int   op = __shfl_xor(p, m);
            if (better(ov, oi, v, i)) { v = ov; i = oi; p = op; }
        }
        if ((tid & 63) == 0) { int w = tid >> 6; sw_v[w] = v; sw_i[w] = i; sw_p[w] = p; }
        __syncthreads();
        if (tid == 0) {
            for (int w = 1; w < 4; w++)
                if (better(sw_v[w], sw_i[w], sw_v[0], sw_i[0])) {
                    sw_v[0] = sw_v[w]; sw_i[0] = sw_i[w]; sw_p[0] = sw_p[w];
                }
            out[k]     = sw_v[0];
            out[5 + k] = (float)sw_i[0];
            s_v[sw_p[0]] = -INFINITY;
        }
        __syncthreads();
    }
}

extern "C" void kernel_launch(void* const* d_in, const int* in_sizes, int n_in,
                              void* d_out, int out_size, void* d_ws, size_t ws_size,
                              hipStream_t stream) {
    const float* W    = (const float*)d_in[0];
    const int*   qidx = (const int*)d_in[1];   // low word of int64 is correct (LE, V < 2^31)
    const int V = in_sizes[0] / 128;

    float* bv = (float*)d_ws;
    int*   bi = (int*)((char*)d_ws + (size_t)NB1 * 5 * sizeof(float));

    sim_block_topk<<<NB1, TPB, 0, stream>>>(W, qidx, V, bv, bi);
    final_topk<<<1, 256, 0, stream>>>(bv, bi, (float*)d_out);
}

// Round 2
// 661.890 us; speedup vs baseline: 1.0086x; 1.0086x over previous
//
#include <hip/hip_runtime.h>
#include <math.h>

#define NB1 1024          // blocks in pass 1
#define TPB 256           // threads per block
#define WAVES_PER_BLOCK (TPB / 64)
#define GROUPS_PER_WAVE 16                      // 4 lanes per row-group
#define TOTAL_GROUPS (NB1 * WAVES_PER_BLOCK * GROUPS_PER_WAVE)   // 65536
#define NLEAD (TPB / 4)                         // leaders per block = 64
#define NBCAND (NLEAD * 5)                      // 320 block-local candidates
#define NCAND (NB1 * 5)                         // 5120 global candidates

constexpr float EPS = 1e-6f;

__device__ __forceinline__ bool better(float v, int i, float bv, int bi) {
    // strictly-greater wins; on exact tie, lower row index wins (jax top_k order)
    return (v > bv) || (v == bv && i < bi);
}

__global__ __launch_bounds__(TPB) void sim_block_topk(
    const float* __restrict__ W, const int* __restrict__ qidx,
    int V, float* __restrict__ bv, int* __restrict__ bi)
{
    const int tid  = threadIdx.x;
    const int lane = tid & 63;
    const int sub  = lane & 3;                  // chunk id within 4-lane group
    const int grp  = lane >> 2;                 // group within wave, 0..15
    const int wave = tid >> 6;
    const int groupGlobal =
        (blockIdx.x * WAVES_PER_BLOCK + wave) * GROUPS_PER_WAVE + grp;

    const int q = qidx[0];

    // q fragment: lane covers elements {sub*4 + j*16 .. +3} for j=0..7 (32 floats)
    float4 qv[8];
    const float4* Q4 = (const float4*)(W + (size_t)q * 128);
    #pragma unroll
    for (int j = 0; j < 8; j++) qv[j] = Q4[sub + 4 * j];

    float qn2 = 0.f;
    #pragma unroll
    for (int j = 0; j < 8; j++)
        qn2 += qv[j].x*qv[j].x + qv[j].y*qv[j].y + qv[j].z*qv[j].z + qv[j].w*qv[j].w;
    qn2 += __shfl_xor(qn2, 1);
    qn2 += __shfl_xor(qn2, 2);
    const float qn = sqrtf(qn2);

    // per-leader register top-5 (constant-indexed after unroll -> stays in VGPRs)
    float tv[5]; int ti[5];
    #pragma unroll
    for (int j = 0; j < 5; j++) { tv[j] = -INFINITY; ti[j] = 0x7fffffff; }

    for (int row = groupGlobal; row < V; row += TOTAL_GROUPS) {
        const float4* Wr = (const float4*)(W + (size_t)row * 128);
        float dot = 0.f, nr = 0.f;
        #pragma unroll
        for (int j = 0; j < 8; j++) {
            float4 wv = Wr[sub + 4 * j];        // 8 independent dwordx4 loads
            dot += wv.x*qv[j].x + wv.y*qv[j].y + wv.z*qv[j].z + wv.w*qv[j].w;
            nr  += wv.x*wv.x   + wv.y*wv.y   + wv.z*wv.z   + wv.w*wv.w;
        }
        // only 2 shfl stages per quantity (4-lane group)
        dot += __shfl_xor(dot, 1); dot += __shfl_xor(dot, 2);
        nr  += __shfl_xor(nr,  1); nr  += __shfl_xor(nr,  2);
        if (sub == 0) {
            float sim = dot / fmaxf(qn * sqrtf(nr), EPS);
            if (sim > tv[4]) {                  // common-case reject
                float nv = sim; int ni = row;
                #pragma unroll
                for (int j = 0; j < 5; j++) {   // bubble-insert, keeps sorted desc
                    bool b = better(nv, ni, tv[j], ti[j]);
                    float ov = tv[j]; int oi = ti[j];
                    if (b) { tv[j] = nv; ti[j] = ni; nv = ov; ni = oi; }
                }
            }
        }
    }

    // ---- block combine: 64 leaders x 5 -> block top-5 (parallel argmax) ----
    __shared__ float s_v[NBCAND];
    __shared__ int   s_i[NBCAND];
    __shared__ float sw_v[WAVES_PER_BLOCK];
    __shared__ int   sw_i[WAVES_PER_BLOCK], sw_p[WAVES_PER_BLOCK];

    if (sub == 0) {
        const int leader = tid >> 2;
        #pragma unroll
        for (int j = 0; j < 5; j++) { s_v[leader*5 + j] = tv[j]; s_i[leader*5 + j] = ti[j]; }
    }
    __syncthreads();

    for (int k = 0; k < 5; k++) {
        float v = -INFINITY; int i = 0x7fffffff; int p = 0;
        for (int e = tid; e < NBCAND; e += TPB) {
            if (better(s_v[e], s_i[e], v, i)) { v = s_v[e]; i = s_i[e]; p = e; }
        }
        #pragma unroll
        for (int m = 32; m >= 1; m >>= 1) {
            float ov = __shfl_xor(v, m);
            int   oi = __shfl_xor(i, m);
            int   op = __shfl_xor(p, m);
            if (better(ov, oi, v, i)) { v = ov; i = oi; p = op; }
        }
        if (lane == 0) { sw_v[wave] = v; sw_i[wave] = i; sw_p[wave] = p; }
        __syncthreads();
        if (tid == 0) {
            for (int w = 1; w < WAVES_PER_BLOCK; w++)
                if (better(sw_v[w], sw_i[w], sw_v[0], sw_i[0])) {
                    sw_v[0] = sw_v[w]; sw_i[0] = sw_i[w]; sw_p[0] = sw_p[w];
                }
            bv[blockIdx.x*5 + k] = sw_v[0];
            bi[blockIdx.x*5 + k] = sw_i[0];
            s_v[sw_p[0]] = -INFINITY;
        }
        __syncthreads();
    }
}

__global__ __launch_bounds__(256) void final_topk(
    const float* __restrict__ bv, const int* __restrict__ bi,
    float* __restrict__ out)
{
    __shared__ float s_v[NCAND];
    __shared__ int   s_i[NCAND];
    __shared__ float sw_v[4];
    __shared__ int   sw_i[4], sw_p[4];

    const int tid = threadIdx.x;
    for (int e = tid; e < NCAND; e += 256) { s_v[e] = bv[e]; s_i[e] = bi[e]; }
    __syncthreads();

    for (int k = 0; k < 5; k++) {
        float v = -INFINITY; int i = 0x7fffffff; int p = 0;
        for (int e = tid; e < NCAND; e += 256) {
            if (better(s_v[e], s_i[e], v, i)) { v = s_v[e]; i = s_i[e]; p = e; }
        }
        #pragma unroll
        for (int m = 32; m >= 1; m >>= 1) {
            float ov = __shfl_xor(v, m);
            int   oi = __shfl_xor(i, m);
            int   op = __shfl_xor(p, m);
            if (better(ov, oi, v, i)) { v = ov; i = oi; p = op; }
        }
        if ((tid & 63) == 0) { int w = tid >> 6; sw_v[w] = v; sw_i[w] = i; sw_p[w] = p; }
        __syncthreads();
        if (tid == 0) {
            for (int w = 1; w < 4; w++)
                if (better(sw_v[w], sw_i[w], sw_v[0], sw_i[0])) {
                    sw_v[0] = sw_v[w]; sw_i[0] = sw_i[w]; sw_p[0] = sw_p[w];
                }
            out[k]     = sw_v[0];
            out[5 + k] = (float)sw_i[0];
            s_v[sw_p[0]] = -INFINITY;
        }
        __syncthreads();
    }
}

extern "C" void kernel_launch(void* const* d_in, const int* in_sizes, int n_in,
                              void* d_out, int out_size, void* d_ws, size_t ws_size,
                              hipStream_t stream) {
    const float* W    = (const float*)d_in[0];
    const int*   qidx = (const int*)d_in[1];   // low word of int64 is correct (LE, V < 2^31)
    const int V = in_sizes[0] / 128;

    float* bv = (float*)d_ws;
    int*   bi = (int*)((char*)d_ws + (size_t)NB1 * 5 * sizeof(float));

    sim_block_topk<<<NB1, TPB, 0, stream>>>(W, qidx, V, bv, bi);
    final_topk<<<1, 256, 0, stream>>>(bv, bi, (float*)d_out);
}